// Round 1
// baseline (325.261 us; speedup 1.0000x reference)
//
#include <hip/hip_runtime.h>

// ---------------- types / helpers ----------------
typedef short bf8s __attribute__((ext_vector_type(8)));   // 8 bf16 (4 VGPRs)
typedef float f32x4 __attribute__((ext_vector_type(4)));

#define MFMA16(a, b, c) __builtin_amdgcn_mfma_f32_16x16x32_bf16(a, b, c, 0, 0, 0)

constexpr int S_ = 512, HID_ = 128, B_ = 128, M_ = B_ * S_;

__device__ inline short f2bf(float f) {  // fp32 -> bf16 (RNE)
  unsigned u = __float_as_uint(f);
  u = (u + 0x7fffu + ((u >> 16) & 1u)) >> 16;
  return (short)u;
}
__device__ inline float bf2f(short s) {
  return __uint_as_float(((unsigned)(unsigned short)s) << 16);
}

__device__ inline float block_red1024(float v, float* red) {
  #pragma unroll
  for (int m = 32; m >= 1; m >>= 1) v += __shfl_xor(v, m);
  __syncthreads();
  if ((threadIdx.x & 63) == 0) red[threadIdx.x >> 6] = v;
  __syncthreads();
  float t = 0.f;
  #pragma unroll
  for (int i = 0; i < 16; ++i) t += red[i];
  return t;
}

// matrix table. doff layout (shorts):
//  per-layer QKV contiguous: l*49152 + {q:0,k:16384,v:32768}
//  ao: 98304 + l*16384 ; iw: 131072 + l*65536 ; fow: 262144 + l*65536 ; clf: 393216
__device__ inline void mat_info(int mat, const float* qw, const float* kw,
                                const float* vw, const float* aow, const float* iw,
                                const float* fw, const float* cw,
                                const float** src, int* n, int* doff) {
  if (mat < 6) {
    int l = mat / 3, which = mat % 3;
    const float* t[3] = {qw, kw, vw};
    *src = t[which] + l * 16384; *n = 16384; *doff = l * 49152 + which * 16384;
  } else if (mat < 8) {
    int l = mat - 6;
    *src = aow + l * 16384; *n = 16384; *doff = 98304 + l * 16384;
  } else if (mat < 10) {
    *src = iw + (mat - 8) * 65536; *n = 65536; *doff = 131072 + (mat - 8) * 65536;
  } else if (mat < 12) {
    *src = fw + (mat - 10) * 65536; *n = 65536; *doff = 262144 + (mat - 10) * 65536;
  } else {
    *src = cw; *n = 256; *doff = 393216;
  }
}

// ---------------- fused quant (blocks 0..12) + embed (blocks 13..) ----------------
__global__ __launch_bounds__(1024) void k_qe(const float* qw, const float* kw,
    const float* vw, const float* aow, const float* iw, const float* fw,
    const float* cw, short* WQ,
    const int* __restrict__ ids, const float* __restrict__ tok,
    const float* __restrict__ pos, const float* __restrict__ g,
    const float* __restrict__ bb, short* xb) {
  __shared__ float red[16];
  int tid = threadIdx.x;
  if (blockIdx.x < 13) {  // ---- ternary quantization ----
    const float* src; int n, doff;
    mat_info(blockIdx.x, qw, kw, vw, aow, iw, fw, cw, &src, &n, &doff);
    float s = 0.f;
    for (int i = tid; i < n; i += 1024) s += fabsf(src[i]);
    s = block_red1024(s, red);
    float delta = 0.7f * s / (float)n;
    float s2 = 0.f, c2 = 0.f;
    for (int i = tid; i < n; i += 1024) {
      float a = fabsf(src[i]);
      if (a > delta) { s2 += a; c2 += 1.f; }
    }
    s2 = block_red1024(s2, red);
    c2 = block_red1024(c2, red);
    float alpha = s2 / fmaxf(c2, 1.f);
    for (int i = tid; i < n; i += 1024) {
      float w = src[i];
      WQ[doff + i] = (fabsf(w) > delta) ? f2bf(w > 0.f ? alpha : -alpha) : (short)0;
    }
  } else {  // ---- embedding + LN ----
    int wave = tid >> 6, lane = tid & 63;
    int t = (blockIdx.x - 13) * 16 + wave;
    int s = t & (S_ - 1);
    int id = ids[t];
    float e0 = tok[(size_t)id * HID_ + lane] + pos[(size_t)s * HID_ + lane];
    float e1 = tok[(size_t)id * HID_ + 64 + lane] + pos[(size_t)s * HID_ + 64 + lane];
    float sum = e0 + e1, ssq = e0 * e0 + e1 * e1;
    #pragma unroll
    for (int m = 32; m >= 1; m >>= 1) {
      sum += __shfl_xor(sum, m);
      ssq += __shfl_xor(ssq, m);
    }
    float mean = sum / 128.f;
    float var = ssq / 128.f - mean * mean;
    float rs = rsqrtf(var + 1e-5f);
    size_t o = (size_t)t * HID_;
    xb[o + lane]      = f2bf((e0 - mean) * rs * g[lane] + bb[lane]);
    xb[o + 64 + lane] = f2bf((e1 - mean) * rs * g[64 + lane] + bb[64 + lane]);
  }
}

// ---------------- QKV linear (layer 0 only): 64-tok blocks, stride-144 LDS ----------------
__global__ __launch_bounds__(256) void k_qkv(
    const short* __restrict__ A, const short* __restrict__ W,
    const float* __restrict__ b0, const float* __restrict__ b1,
    const float* __restrict__ b2, short* outb) {
  __shared__ short Wl[128 * 144];  // 144 shorts = 72 words (8 mod 32): 4-way not 8-way
  int tid = threadIdx.x, lane = tid & 63, wave = tid >> 6;
  int row16 = lane & 15, quad = lane >> 4;
  int tok0 = blockIdx.x * 64 + wave * 16;
  int nbase = blockIdx.y * 128;

  const short* arow = A + (size_t)(tok0 + row16) * 128 + quad * 8;
  bf8s av[4];
  #pragma unroll
  for (int ki = 0; ki < 4; ++ki) av[ki] = *(const bf8s*)(arow + ki * 32);

  {
    int r = tid >> 1, half = tid & 1;
    const short* src = W + (size_t)(nbase + r) * 128 + half * 64;
    short* dst = &Wl[r * 144 + half * 64];
    #pragma unroll
    for (int j = 0; j < 8; ++j)
      *(bf8s*)(dst + j * 8) = *(const bf8s*)(src + j * 8);
  }
  __syncthreads();

  f32x4 acc[8] = {};
  #pragma unroll
  for (int ki = 0; ki < 4; ++ki)
    #pragma unroll
    for (int ot = 0; ot < 8; ++ot) {
      bf8s b = *(const bf8s*)(&Wl[(ot * 16 + row16) * 144 + ki * 32 + quad * 8]);
      acc[ot] = MFMA16(av[ki], b, acc[ot]);
    }

  const float* bp = (blockIdx.y == 0) ? b0 : ((blockIdx.y == 1) ? b1 : b2);
  float osc = (blockIdx.y == 0) ? 0.125f : 1.0f;  // fold 1/sqrt(64) into Q
  int m0 = tok0 + quad * 4;
  #pragma unroll
  for (int ot = 0; ot < 8; ++ot) {
    int col = ot * 16 + row16;
    float bi = bp[col];
    #pragma unroll
    for (int r = 0; r < 4; ++r) {
      float v = (acc[ot][r] + bi) * osc;
      outb[(size_t)(m0 + r) * 384 + nbase + col] = f2bf(v);
    }
  }
}

// ---------------- fused AO+LN1+FF1+FF2+LN2 [+ next-layer QKV] ----------------
// Round-15 (latency-bound fix; was MfmaUtil 17 / VALU 26 / HBM 22 -> ~58% all-idle):
//  * x' spill to xb ELIMINATED: kept packed bf16x2 in 16 VGPRs (xp[16]).
//    Removes 33.6 MB HBM round-trip + 64 scalar VMEM/lane + store-drain at barrier.
//    Numerics identical (same f2bf rounding as old spill/reload).
//  * All 11 staged chunks (8 FF + 3 QKV) reg-prefetched ONE chunk ahead (k_attn
//    pattern): loads issue under previous chunk's MFMAs; the next barrier's
//    vmcnt(0) drain then finds them already complete. FF c=0 prefetched during
//    phase-A epilogue; QKV c3=0 prefetched during FF c=7.
//  * AO residual loads hoisted ahead of phase-A MFMAs (were serial in epilogue).
//  * Final xb write widened to 4x bf8s/lane via the myX transpose (both paths).
//  * __launch_bounds__(512,4): cap VGPR at 128 (exactly 4 waves/SIMD) so the
//    LDS-bound 2 blocks/CU residency survives ~105-reg peak pressure
//    (acc2 32 + av 16 + xp 16 + pf 16 + transients).
// LDS unchanged: phase A Wa 128x144=18432sh | FF: SWi 64x144=9216 +
// SWf 128x80=10240 + stash 8x16x80=10240 = 29696sh (59392 B) -> 2 blocks/CU.
template <int DOQKV>
__global__ __launch_bounds__(512, 4) void k_aoff(
    const short* __restrict__ cb, const short* __restrict__ Wa,
    const float* __restrict__ aob, const float* __restrict__ ln1g,
    const float* __restrict__ ln1b, const short* __restrict__ Wi,
    const short* __restrict__ Wf, const float* __restrict__ ib,
    const float* __restrict__ fb, const float* __restrict__ ln2g,
    const float* __restrict__ ln2b, short* xb,
    const short* __restrict__ Wqkv2, const float* __restrict__ qb2,
    const float* __restrict__ kb2, const float* __restrict__ vb2,
    short* qkvout) {
  __shared__ short SM[29696];
  int tid = threadIdx.x, lane = tid & 63, wave = tid >> 6;
  int row16 = lane & 15, quad = lane >> 4;
  int tok0 = blockIdx.x * 128 + wave * 16;
  int m0 = tok0 + quad * 4;
  int rs4 = tid >> 2, q4 = tid & 3;   // 4 threads/row staging pattern
  int rwi = tid >> 3, q8 = tid & 7;   // Wi: 64 rows x 8 groups of 16 shorts

  // ---- phase A: AO linear ----
  const short* arow = cb + (size_t)(tok0 + row16) * 128 + quad * 8;
  bf8s av[4];
  #pragma unroll
  for (int ki = 0; ki < 4; ++ki) av[ki] = *(const bf8s*)(arow + ki * 32);

  {  // stage Wa 128x128 (stride 144): 4 threads/row, 32 shorts each
    const short* src = Wa + (size_t)rs4 * 128 + q4 * 32;
    short* dst = &SM[rs4 * 144 + q4 * 32];
    #pragma unroll
    for (int j = 0; j < 4; ++j)
      *(bf8s*)(dst + j * 8) = *(const bf8s*)(src + j * 8);
  }

  // hoisted residual loads: latency hides under Wa staging + phase-A MFMAs
  float resid[8][4];
  #pragma unroll
  for (int ot = 0; ot < 8; ++ot) {
    int col = ot * 16 + row16;
    #pragma unroll
    for (int r = 0; r < 4; ++r)
      resid[ot][r] = bf2f(xb[(size_t)(m0 + r) * HID_ + col]);
  }
  __syncthreads();

  f32x4 acc[8] = {};
  #pragma unroll
  for (int ki = 0; ki < 4; ++ki)
    #pragma unroll
    for (int ot = 0; ot < 8; ++ot) {
      bf8s b = *(const bf8s*)(&SM[(ot * 16 + row16) * 144 + ki * 32 + quad * 8]);
      acc[ot] = MFMA16(av[ki], b, acc[ot]);
    }

  // prefetch FF chunk 0 (consumed after two barriers; hides under epilogue)
  bf8s pf0, pf1, pf2, pf3;
  {
    const short* ws1 = Wi + (size_t)rwi * HID_ + q8 * 16;
    const short* ws2 = Wf + (size_t)rs4 * 512 + q4 * 16;
    pf0 = *(const bf8s*)(ws1); pf1 = *(const bf8s*)(ws1 + 8);
    pf2 = *(const bf8s*)(ws2); pf3 = *(const bf8s*)(ws2 + 8);
  }

  // AO epilogue: bias + residual + LN1 -> x'
  {
    float sum[4] = {}, ssq[4] = {};
    #pragma unroll
    for (int ot = 0; ot < 8; ++ot) {
      int col = ot * 16 + row16;
      float bi = aob[col];
      #pragma unroll
      for (int r = 0; r < 4; ++r) {
        float v = acc[ot][r] + bi + resid[ot][r];
        acc[ot][r] = v;
        sum[r] += v; ssq[r] += v * v;
      }
    }
    #pragma unroll
    for (int m = 1; m <= 8; m <<= 1)
      #pragma unroll
      for (int r = 0; r < 4; ++r) {
        sum[r] += __shfl_xor(sum[r], m);
        ssq[r] += __shfl_xor(ssq[r], m);
      }
    float mean[4], rstd[4];
    #pragma unroll
    for (int r = 0; r < 4; ++r) {
      mean[r] = sum[r] / 128.f;
      float var = ssq[r] / 128.f - mean[r] * mean[r];
      rstd[r] = rsqrtf(var + 1e-5f);
    }
    #pragma unroll
    for (int ot = 0; ot < 8; ++ot) {
      int col = ot * 16 + row16;
      float gg = ln1g[col], bb2 = ln1b[col];
      #pragma unroll
      for (int r = 0; r < 4; ++r)
        acc[ot][r] = (acc[ot][r] - mean[r]) * rstd[r] * gg + bb2;  // x'
    }
  }

  // pack x' to bf16x2 in 16 regs -- replaces the 33.6 MB global spill round-trip
  unsigned xp[16];
  #pragma unroll
  for (int ot = 0; ot < 8; ++ot) {
    xp[2 * ot] = (unsigned)(unsigned short)f2bf(acc[ot][0]) |
                 ((unsigned)(unsigned short)f2bf(acc[ot][1]) << 16);
    xp[2 * ot + 1] = (unsigned)(unsigned short)f2bf(acc[ot][2]) |
                     ((unsigned)(unsigned short)f2bf(acc[ot][3]) << 16);
  }

  // transpose x' -> A-frags through the (dead) Wa region; wave-private slice
  __syncthreads();
  short* myX = &SM[wave * 2304];  // 16 rows x stride 144
  {
    #pragma unroll
    for (int ot = 0; ot < 8; ++ot) {
      int col = ot * 16 + row16;
      myX[(quad * 4 + 0) * 144 + col] = (short)(xp[2 * ot] & 0xffffu);
      myX[(quad * 4 + 1) * 144 + col] = (short)(xp[2 * ot] >> 16);
      myX[(quad * 4 + 2) * 144 + col] = (short)(xp[2 * ot + 1] & 0xffffu);
      myX[(quad * 4 + 3) * 144 + col] = (short)(xp[2 * ot + 1] >> 16);
    }
    #pragma unroll
    for (int ki = 0; ki < 4; ++ki)
      av[ki] = *(const bf8s*)(myX + row16 * 144 + ki * 32 + quad * 8);
  }

  // ---- phase B: FF over 8 inter-chunks, one-chunk-ahead reg prefetch ----
  short* SWi = SM;                         // 64 x 144
  short* SWf = SM + 9216;                  // 128 x 80
  short* mySt = SM + 19456 + wave * 1280;  // 16 x 80 per wave
  f32x4 acc2[8] = {};
  for (int c = 0; c < 8; ++c) {
    __syncthreads();  // prev chunk LDS reads (or myX av reads) done; pf complete
    {
      short* dwi = SWi + rwi * 144 + q8 * 16;
      short* dwf = SWf + rs4 * 80 + q4 * 16;
      *(bf8s*)(dwi) = pf0; *(bf8s*)(dwi + 8) = pf1;
      *(bf8s*)(dwf) = pf2; *(bf8s*)(dwf + 8) = pf3;
    }
    __syncthreads();
    if (c < 7) {  // prefetch next FF chunk under this chunk's MFMAs
      const short* ws1 = Wi + (size_t)((c + 1) * 64 + rwi) * HID_ + q8 * 16;
      const short* ws2 = Wf + (size_t)rs4 * 512 + (c + 1) * 64 + q4 * 16;
      pf0 = *(const bf8s*)(ws1); pf1 = *(const bf8s*)(ws1 + 8);
      pf2 = *(const bf8s*)(ws2); pf3 = *(const bf8s*)(ws2 + 8);
    } else if (DOQKV) {  // prefetch QKV chunk 0 under last FF chunk + epilogue
      const short* src = Wqkv2 + (size_t)rs4 * 128 + q4 * 32;
      pf0 = *(const bf8s*)(src);      pf1 = *(const bf8s*)(src + 8);
      pf2 = *(const bf8s*)(src + 16); pf3 = *(const bf8s*)(src + 24);
    }

    // FF1 sequentialized: one 16x16 tile at a time (peak hacc liveness = 4 regs)
    #pragma unroll
    for (int ot = 0; ot < 4; ++ot) {
      f32x4 hacc = {};
      #pragma unroll
      for (int ki = 0; ki < 4; ++ki) {
        bf8s b = *(const bf8s*)(SWi + (ot * 16 + row16) * 144 + ki * 32 + quad * 8);
        hacc = MFMA16(av[ki], b, hacc);
      }
      float bi = ib[c * 64 + ot * 16 + row16];
      #pragma unroll
      for (int r = 0; r < 4; ++r)
        mySt[(quad * 4 + r) * 80 + ot * 16 + row16] =
            f2bf(fmaxf(hacc[r] + bi, 0.f));
    }
    bf8s ha0 = *(const bf8s*)(mySt + row16 * 80 + quad * 8);
    bf8s ha1 = *(const bf8s*)(mySt + row16 * 80 + 32 + quad * 8);
    #pragma unroll
    for (int ot = 0; ot < 8; ++ot) {
      bf8s bA = *(const bf8s*)(SWf + (ot * 16 + row16) * 80 + quad * 8);
      bf8s bB = *(const bf8s*)(SWf + (ot * 16 + row16) * 80 + 32 + quad * 8);
      acc2[ot] = MFMA16(ha0, bA, acc2[ot]);
      acc2[ot] = MFMA16(ha1, bB, acc2[ot]);
    }
  }

  // FF epilogue: + fb + x'(from regs) + LN2 -> x'' in acc2
  {
    float sum[4] = {}, ssq[4] = {};
    #pragma unroll
    for (int ot = 0; ot < 8; ++ot) {
      int col = ot * 16 + row16;
      float bi = fb[col];
      #pragma unroll
      for (int r = 0; r < 4; ++r) {
        unsigned u = xp[2 * ot + (r >> 1)];
        float xv = (r & 1) ? __uint_as_float(u & 0xffff0000u)
                           : __uint_as_float(u << 16);
        float v = acc2[ot][r] + bi + xv;
        acc2[ot][r] = v;
        sum[r] += v; ssq[r] += v * v;
      }
    }
    #pragma unroll
    for (int m = 1; m <= 8; m <<= 1)
      #pragma unroll
      for (int r = 0; r < 4; ++r) {
        sum[r] += __shfl_xor(sum[r], m);
        ssq[r] += __shfl_xor(ssq[r], m);
      }
    float mean[4], rstd[4];
    #pragma unroll
    for (int r = 0; r < 4; ++r) {
      mean[r] = sum[r] / 128.f;
      float var = ssq[r] / 128.f - mean[r] * mean[r];
      rstd[r] = rsqrtf(var + 1e-5f);
    }
    #pragma unroll
    for (int ot = 0; ot < 8; ++ot) {
      int col = ot * 16 + row16;
      float gg = ln2g[col], bb2 = ln2b[col];
      #pragma unroll
      for (int r = 0; r < 4; ++r)
        acc2[ot][r] = (acc2[ot][r] - mean[r]) * rstd[r] * gg + bb2;
    }
  }

  // transpose x'' through myX; wide coalesced xb write (both DOQKV paths)
  __syncthreads();  // all FF LDS reads done
  #pragma unroll
  for (int ot = 0; ot < 8; ++ot) {
    int col = ot * 16 + row16;
    #pragma unroll
    for (int r = 0; r < 4; ++r)
      myX[(quad * 4 + r) * 144 + col] = f2bf(acc2[ot][r]);
  }
  {
    int xr = lane >> 2, xs = (lane & 3) * 32;
    short* xrow = xb + (size_t)(tok0 + xr) * HID_ + xs;
    #pragma unroll
    for (int j = 0; j < 4; ++j)
      *(bf8s*)(xrow + j * 8) = *(const bf8s*)(myX + xr * 144 + xs + j * 8);
  }

  if (DOQKV) {
    // ---- tail: next-layer QKV for our own 128 tokens ----
    bf8s av2[4];
    #pragma unroll
    for (int ki = 0; ki < 4; ++ki)
      av2[ki] = *(const bf8s*)(myX + row16 * 144 + ki * 32 + quad * 8);
    for (int c3 = 0; c3 < 3; ++c3) {
      __syncthreads();  // myX reads done (c3==0) / prev chunk reads; pf complete
      {  // stage Wqkv chunk 128x128 (stride 144) from prefetched regs
        short* dst = &SM[rs4 * 144 + q4 * 32];
        *(bf8s*)(dst) = pf0;      *(bf8s*)(dst + 8) = pf1;
        *(bf8s*)(dst + 16) = pf2; *(bf8s*)(dst + 24) = pf3;
      }
      __syncthreads();
      if (c3 < 2) {  // prefetch next QKV chunk under this chunk's MFMAs
        const short* src = Wqkv2 + (size_t)((c3 + 1) * 128 + rs4) * 128 + q4 * 32;
        pf0 = *(const bf8s*)(src);      pf1 = *(const bf8s*)(src + 8);
        pf2 = *(const bf8s*)(src + 16); pf3 = *(const bf8s*)(src + 24);
      }
      f32x4 acc3[8] = {};
      #pragma unroll
      for (int ki = 0; ki < 4; ++ki)
        #pragma unroll
        for (int ot = 0; ot < 8; ++ot) {
          bf8s b = *(const bf8s*)(&SM[(ot * 16 + row16) * 144 + ki * 32 + quad * 8]);
          acc3[ot] = MFMA16(av2[ki], b, acc3[ot]);
        }
      const float* bp = (c3 == 0) ? qb2 : ((c3 == 1) ? kb2 : vb2);
      float osc = (c3 == 0) ? 0.125f : 1.0f;
      #pragma unroll
      for (int ot = 0; ot < 8; ++ot) {
        int col = ot * 16 + row16;
        float bi = bp[col];
        #pragma unroll
        for (int r = 0; r < 4; ++r) {
          float v = (acc3[ot][r] + bi) * osc;
          qkvout[(size_t)(m0 + r) * 384 + c3 * 128 + col] = f2bf(v);
        }
      }
    }
  }
}

// ---------------- flash attention (round-12, unchanged) ----------------
// grid = 512: blockIdx.x = (b<<2)|(h<<1)|qhalf. block = 512 (8 waves x 32 queries).
// LDS 36864 B -> 4 blocks/CU. Next stage's K/V reg-prefetched after the barrier.
// No-max softmax (Q pre-scaled; tiny scores). li per-lane, reduced in epilogue.
__global__ __launch_bounds__(512) void k_attn(const short* __restrict__ qkv,
                                              short* __restrict__ O) {
  __shared__ short Kl[64 * 72];     // 64 keys x 64 d, stride 72
  __shared__ short Vtl[64 * 72];    // 64 d x 64 keys, stride 72
  __shared__ short Pl[8][16 * 72];  // per-wave P stash (16 q x 64 k)

  int tid = threadIdx.x, lane = tid & 63, wave = tid >> 6;
  int row16 = lane & 15, quad = lane >> 4;
  int b = blockIdx.x >> 2, h = (blockIdx.x >> 1) & 1, qhalf = blockIdx.x & 1;
  const short* base  = qkv + (size_t)b * S_ * 384;
  const short* kbase = base + 128 + h * 64;
  const short* vbase = base + 256 + h * 64;
  int q0 = qhalf * 256 + wave * 32;

  bf8s qa[2][2];
  #pragma unroll
  for (int qf = 0; qf < 2; ++qf) {
    const short* qrow = base + h * 64 +
        (size_t)(q0 + qf * 16 + row16) * 384 + quad * 8;
    qa[qf][0] = *(const bf8s*)(qrow);
    qa[qf][1] = *(const bf8s*)(qrow + 32);
  }

  int krow = tid >> 3, dgk = tid & 7;
  int vkey = tid & 63, dgv = tid >> 6;
  const short* kptr = kbase + (size_t)krow * 384 + dgk * 8;
  const short* vptr = vbase + (size_t)vkey * 384 + dgv * 8;
  bf8s kst = *(const bf8s*)(kptr);
  bf8s vst = *(const bf8s*)(vptr);

  float li[2][4] = {};
  f32x4 oacc[2][4] = {};
  short* myP = &Pl[wave][0];

  for (int kt0 = 0; kt0 < S_; kt0 += 64) {
    if (kt0) __syncthreads();
    *(bf8s*)(&Kl[krow * 72 + dgk * 8]) = kst;
    #pragma unroll
    for (int j = 0; j < 8; ++j) Vtl[(dgv * 8 + j) * 72 + vkey] = vst[j];
    __syncthreads();
    if (kt0 + 64 < S_) {
      kst = *(const bf8s*)(kptr + (size_t)(kt0 + 64) * 384);
      vst = *(const bf8s*)(vptr + (size_t)(kt0 + 64) * 384);
    }

    f32x4 sc[2][4] = {};
    #pragma unroll
    for (int ks = 0; ks < 4; ++ks) {
      const short* kp = &Kl[(ks * 16 + row16) * 72 + quad * 8];
      bf8s k0 = *(const bf8s*)(kp);
      bf8s k1 = *(const bf8s*)(kp + 32);
      sc[0][ks] = MFMA16(qa[0][0], k0, sc[0][ks]);
      sc[0][ks] = MFMA16(qa[0][1], k1, sc[0][ks]);
      sc[1][ks] = MFMA16(qa[1][0], k0, sc[1][ks]);
      sc[1][ks] = MFMA16(qa[1][1], k1, sc[1][ks]);
    }

    #pragma unroll
    for (int qf = 0; qf < 2; ++qf) {
      #pragma unroll
      for (int ks = 0; ks < 4; ++ks)
        #pragma unroll
        for (int r = 0; r < 4; ++r) {
          float pv = __expf(sc[qf][ks][r]);
          li[qf][r] += pv;
          myP[(quad * 4 + r) * 72 + ks * 16 + row16] = f2bf(pv);
        }
      bf8s pa0 = *(const bf8s*)(&myP[row16 * 72 + quad * 8]);
      bf8s pa1 = *(const bf8s*)(&myP[row16 * 72 + 32 + quad * 8]);
      #pragma unroll
      for (int dt = 0; dt < 4; ++dt) {
        const short* vp = &Vtl[(dt * 16 + row16) * 72 + quad * 8];
        bf8s v0 = *(const bf8s*)(vp);
        bf8s v1 = *(const bf8s*)(vp + 32);
        oacc[qf][dt] = MFMA16(pa0, v0, oacc[qf][dt]);
        oacc[qf][dt] = MFMA16(pa1, v1, oacc[qf][dt]);
      }
    }
  }

  #pragma unroll
  for (int qf = 0; qf < 2; ++qf) {
    float inv[4];
    #pragma unroll
    for (int r = 0; r < 4; ++r) {
      float t = li[qf][r];
      #pragma unroll
      for (int m = 1; m <= 8; m <<= 1) t += __shfl_xor(t, m);
      inv[r] = 1.f / t;
    }
    size_t trow = (size_t)(b * S_ + q0 + qf * 16 + quad * 4);
    #pragma unroll
    for (int dt = 0; dt < 4; ++dt)
      #pragma unroll
      for (int r = 0; r < 4; ++r)
        O[(trow + r) * HID_ + h * 64 + dt * 16 + row16] =
            f2bf(oacc[qf][dt][r] * inv[r]);
  }
}

// ---------------- classifier ----------------
__global__ __launch_bounds__(256) void k_clf(const short* __restrict__ xb,
    const short* __restrict__ Wc, const float* __restrict__ cbias, float* out) {
  int i = threadIdx.x;  // 256 = 128 batches x 2 classes
  int b = i >> 1, c = i & 1;
  float s = 0.f;
  for (int k = 0; k < HID_; ++k)
    s += bf2f(xb[(size_t)b * S_ * HID_ + k]) * bf2f(Wc[c * HID_ + k]);
  out[b * 2 + c] = s + cbias[c];
}

// ---------------- launcher ----------------
extern "C" void kernel_launch(void* const* d_in, const int* in_sizes, int n_in,
                              void* d_out, int out_size, void* d_ws, size_t ws_size,
                              hipStream_t stream) {
  const int*   ids     = (const int*)d_in[0];
  const float* tok_emb = (const float*)d_in[1];
  const float* pos_emb = (const float*)d_in[2];
  const float* ln_g    = (const float*)d_in[3];
  const float* ln_bb   = (const float*)d_in[4];
  const float* qw      = (const float*)d_in[5];
  const float* qbias   = (const float*)d_in[6];
  const float* kw      = (const float*)d_in[7];
  const float* kbias   = (const float*)d_in[8];
  const float* vw      = (const float*)d_in[9];
  const float* vbias   = (const float*)d_in[10];
  const float* aow     = (const float*)d_in[11];
  const float* aobias  = (const float*)d_in[12];
  const float* iw      = (const float*)d_in[13];
  const float* ibias   = (const float*)d_in[14];
  const float* fow     = (const float*)d_in[15];
  const float* fbias   = (const float*)d_in[16];
  const float* ln1g    = (const float*)d_in[17];
  const float* ln1b    = (const float*)d_in[18];
  const float* ln2g    = (const float*)d_in[19];
  const float* ln2b    = (const float*)d_in[20];
  const float* clfw    = (const float*)d_in[21];
  const float* clfb    = (const float*)d_in[22];

  char* ws = (char*)d_ws;
  short* WQ  = (short*)ws;                                   // 787 KB quantized weights
  short* xb  = (short*)(ws + 1048576);                       // bf16 trunk (16.8 MB)
  short* qkv = (short*)(ws + 1048576 + 16777216);            // [tok][384] (50.3 MB)
  short* cb_ = qkv + (size_t)M_ * 384;                       // ctx [tok][128] (16.8 MB)

  k_qe<<<13 + M_ / 16, 1024, 0, stream>>>(qw, kw, vw, aow, iw, fow, clfw, WQ,
                                          ids, tok_emb, pos_emb, ln_g, ln_bb, xb);

  const short* Wqkv0 = WQ;
  const short* Wqkv1 = WQ + 49152;
  const short* Wa0   = WQ + 98304;
  const short* Wa1   = WQ + 98304 + 16384;
  const short* Wi0   = WQ + 131072;
  const short* Wi1   = WQ + 131072 + 65536;
  const short* Wf0   = WQ + 262144;
  const short* Wf1   = WQ + 262144 + 65536;

  // layer 0 (k_aoff tail computes layer-1 QKV)
  k_qkv<<<dim3(M_ / 64, 3), 256, 0, stream>>>(
      xb, Wqkv0, qbias, kbias, vbias, qkv);
  k_attn<<<512, 512, 0, stream>>>(qkv, cb_);
  k_aoff<1><<<M_ / 128, 512, 0, stream>>>(
      cb_, Wa0, aobias, ln1g, ln1b, Wi0, Wf0, ibias, fbias, ln2g, ln2b, xb,
      Wqkv1, qbias + HID_, kbias + HID_, vbias + HID_, qkv);
  // layer 1
  k_attn<<<512, 512, 0, stream>>>(qkv, cb_);
  k_aoff<0><<<M_ / 128, 512, 0, stream>>>(
      cb_, Wa1, aobias + HID_, ln1g + HID_, ln1b + HID_, Wi1, Wf1,
      ibias + 512, fbias + HID_, ln2g + HID_, ln2b + HID_, xb,
      nullptr, nullptr, nullptr, nullptr, nullptr);

  k_clf<<<1, 256, 0, stream>>>(xb, WQ + 393216, clfb, (float*)d_out);
}